// Round 4
// baseline (445.483 us; speedup 1.0000x reference)
//
#include <hip/hip_runtime.h>
#include <stdint.h>

#define NN 10000
#define NE 320000
#define DF 128
#define OD 128
#define NS 3

// ---- edge locality buckets: 20x20 node-tiles (src>>9, dst>>9), ordered in
// 5x5 supertiles of 4x4 buckets. One supertile's Q slices ~3.1MB -> fits a
// single XCD's 4MB L2. ----
#define NBK 400

typedef __attribute__((ext_vector_type(8))) short bf16x8;
typedef __attribute__((ext_vector_type(16))) float f32x16;

static __device__ __forceinline__ uint32_t f2bf(float f) {
  uint32_t u = __float_as_uint(f);
  return (u + 0x7FFFu + ((u >> 16) & 1u)) >> 16;
}
static __device__ __forceinline__ float bflo(uint32_t u) { return __uint_as_float(u << 16); }
static __device__ __forceinline__ float bfhi(uint32_t u) { return __uint_as_float(u & 0xFFFF0000u); }

static __device__ __forceinline__ uint32_t relu2(uint32_t a, uint32_t d) {
  float f0 = fmaxf(bflo(a) + bflo(d), 0.0f);
  float f1 = fmaxf(bfhi(a) + bfhi(d), 0.0f);
  return f2bf(f0) | (f2bf(f1) << 16);
}

static __device__ __forceinline__ int bkey(int s, int d) {
  int sb = s >> 9, db = d >> 9;                      // 0..19
  return ((sb >> 2) * 5 + (db >> 2)) * 16 + (sb & 3) * 4 + (db & 3);
}

// lgkm-only barrier: orders LDS producer/consumer without draining vmcnt.
static __device__ __forceinline__ void lds_barrier() {
  asm volatile("s_waitcnt lgkmcnt(0)" ::: "memory");
  __builtin_amdgcn_s_barrier();
}

// ---------------------------------------------------------------------------
// Kernel 0: W2 -> fragment-major bf16 W2F + bmean (unchanged from R3)
// ---------------------------------------------------------------------------
__global__ __launch_bounds__(256) void prep_w2(
    const float* __restrict__ W2, const float* __restrict__ b2,
    unsigned short* __restrict__ w2f, float* __restrict__ bmean)
{
  int o = blockIdx.x * 256 + threadIdx.x;
  if (o < NS * 8 * 256 * 8) {
    int j = o & 7;
    int t = (o >> 3) & 255;
    int q = (o >> 11) & 7;
    int s = o >> 14;
    int w = t >> 6, lane = t & 63;
    int n = w * 32 + (lane & 31);
    int k = q * 16 + (lane >> 5) * 8 + j;
    w2f[o] = (unsigned short)f2bf(W2[((size_t)s * OD + k) * OD + n]);
  }
  if (o < OD) bmean[o] = (b2[o] + b2[OD + o] + b2[2 * OD + o]) * (1.0f / 3.0f);
}

// ---------------------------------------------------------------------------
// Kernel 1: per-node projections (unchanged — ~7 us)
// ---------------------------------------------------------------------------
__global__ __launch_bounds__(256) void node_proj(
    const float* __restrict__ nf, const float* __restrict__ temporal,
    const float* __restrict__ W1, const float* __restrict__ b1,
    unsigned short* __restrict__ Qsrc, unsigned short* __restrict__ Qdst)
{
  __shared__ unsigned short Asm[8 * 64 * 8];
  __shared__ unsigned short Bsm[4 * 8 * 64 * 8];
  __shared__ float tsh[32];

  const int t = threadIdx.x;
  const int c = blockIdx.y;
  const int s = c >> 1, proj = c & 1;

  {
    int o = t & 127, qh = t >> 7;
    const float* wbase = W1 + (size_t)(s * 257 + proj * 128) * OD + o;
    int nt = o >> 5, lnlo = o & 31;
    #pragma unroll
    for (int r = 0; r < 8; r++) {
      int kh = qh * 8 + r;
      float v[8];
      #pragma unroll
      for (int j = 0; j < 8; j++) v[j] = wbase[(size_t)(kh * 8 + j) * OD];
      uint32_t pk[4];
      #pragma unroll
      for (int i = 0; i < 4; i++) pk[i] = f2bf(v[2 * i]) | (f2bf(v[2 * i + 1]) << 16);
      int q = kh >> 1, half = kh & 1;
      uint32_t* d = (uint32_t*)(Bsm + ((nt * 8 + q) * 64 + half * 32 + lnlo) * 8);
      d[0] = pk[0]; d[1] = pk[1]; d[2] = pk[2]; d[3] = pk[3];
    }
  }

  const int lane = t & 63, w = t >> 6;
  const int o = w * 32 + (lane & 31);
  const float w1gv = W1[(size_t)(s * 257 + 256) * OD + o];
  const float b1v = b1[s * OD + o];
  unsigned short* Qt = (proj == 0) ? Qsrc : Qdst;
  const int m = t >> 3, j16 = t & 7;

  for (int it = 0; it < 8; it++) {
    const int m0 = (blockIdx.x * 8 + it) * 32;
    if (m0 >= NN) break;

    if (t < 32) tsh[t] = (m0 + t < NN) ? temporal[m0 + t] : 0.0f;

    {
      int node = m0 + m;
      float v[16];
      if (node < NN) {
        const float4* p = (const float4*)(nf + (size_t)node * DF + j16 * 16);
        #pragma unroll
        for (int i = 0; i < 4; i++) {
          float4 x = p[i];
          v[4 * i] = x.x; v[4 * i + 1] = x.y; v[4 * i + 2] = x.z; v[4 * i + 3] = x.w;
        }
      } else {
        #pragma unroll
        for (int i = 0; i < 16; i++) v[i] = 0.0f;
      }
      uint32_t pk[8];
      #pragma unroll
      for (int i = 0; i < 8; i++) pk[i] = f2bf(v[2 * i]) | (f2bf(v[2 * i + 1]) << 16);
      uint32_t* d0 = (uint32_t*)(Asm + (j16 * 64 + (m ^ j16)) * 8);
      uint32_t* d1 = (uint32_t*)(Asm + (j16 * 64 + ((32 + m) ^ j16)) * 8);
      d0[0] = pk[0]; d0[1] = pk[1]; d0[2] = pk[2]; d0[3] = pk[3];
      d1[0] = pk[4]; d1[1] = pk[5]; d1[2] = pk[6]; d1[3] = pk[7];
    }
    __syncthreads();

    f32x16 C;
    #pragma unroll
    for (int i = 0; i < 16; i++) C[i] = 0.0f;
    #pragma unroll
    for (int q = 0; q < 8; q++) {
      bf16x8 a = *(const bf16x8*)(Asm + (q * 64 + (lane ^ q)) * 8);
      bf16x8 b = *(const bf16x8*)(Bsm + ((w * 8 + q) * 64 + lane) * 8);
      C = __builtin_amdgcn_mfma_f32_32x32x16_bf16(a, b, C, 0, 0, 0);
    }

    #pragma unroll
    for (int r = 0; r < 16; r++) {
      int row = (r & 3) + 8 * (r >> 2) + 4 * (lane >> 5);
      int node = m0 + row;
      if (node < NN) {
        float val = C[r];
        if (proj == 0) val += b1v + tsh[row] * w1gv;
        else           val -= tsh[row] * w1gv;
        Qt[(size_t)node * (NS * OD) + s * OD + o] = (unsigned short)f2bf(val);
      }
    }
    __syncthreads();
  }
}

// ---------------------------------------------------------------------------
// Edge bucketing: zero -> histogram -> exclusive scan -> scatter.
// Deterministic output: within-bucket order is arbitrary, but each edge's
// result is computed independently and written to its original row.
// ---------------------------------------------------------------------------
__global__ __launch_bounds__(256) void zero_aux(int* __restrict__ gh) {
  int t = blockIdx.x * 256 + threadIdx.x;
  if (t < NBK) gh[t] = 0;
}

__global__ __launch_bounds__(256) void edge_hist(
    const int* __restrict__ ei, int* __restrict__ gh)
{
  __shared__ int h[NBK];
  for (int i = threadIdx.x; i < NBK; i += 256) h[i] = 0;
  __syncthreads();
  int e = blockIdx.x * 256 + threadIdx.x;
  if (e < NE) {
    int s = ei[e], d = ei[NE + e];
    atomicAdd(&h[bkey(s, d)], 1);
  }
  __syncthreads();
  for (int i = threadIdx.x; i < NBK; i += 256)
    if (h[i]) atomicAdd(&gh[i], h[i]);
}

__global__ __launch_bounds__(512) void bucket_scan(
    const int* __restrict__ gh, int* __restrict__ cursor)
{
  __shared__ int sc[512];
  int t = threadIdx.x;
  int own = (t < NBK) ? gh[t] : 0;
  sc[t] = own;
  __syncthreads();
  for (int off = 1; off < 512; off <<= 1) {
    int add = (t >= off) ? sc[t - off] : 0;
    int v = sc[t];
    __syncthreads();
    sc[t] = v + add;
    __syncthreads();
  }
  if (t < NBK) cursor[t] = sc[t] - own;   // exclusive prefix
}

__global__ __launch_bounds__(256) void edge_scatter(
    const int* __restrict__ ei, int* __restrict__ cursor,
    int* __restrict__ es, int* __restrict__ ed, int* __restrict__ eo)
{
  int e = blockIdx.x * 256 + threadIdx.x;
  if (e >= NE) return;
  int s = ei[e], d = ei[NE + e];
  int pos = atomicAdd(&cursor[bkey(s, d)], 1);
  es[pos] = s; ed[pos] = d; eo[pos] = e;
}

// ---------------------------------------------------------------------------
// Kernel 2: edge MLP over BUCKETED edges. R3 structure (VGPR-lean, per-tile
// W2F reload, lgkm barriers, NT stores) + bijective chunked XCD swizzle so
// each XCD walks a contiguous supertile range -> gathers hit L2 slices.
// Output scattered to original edge rows via eo.
// ---------------------------------------------------------------------------
__global__ __launch_bounds__(256, 4) void edge_mlp(
    const unsigned short* __restrict__ Qsrc, const unsigned short* __restrict__ Qdst,
    const unsigned short* __restrict__ W2F, const float* __restrict__ bmean,
    const int* __restrict__ es, const int* __restrict__ ed,
    const int* __restrict__ eo, float* __restrict__ out)
{
  __shared__ unsigned short hsm[NS * 8 * 64 * 8];   // 24 KB, swizzled frag layout

  const int t = threadIdx.x;
  const int lane = t & 63, w = t >> 6;
  const int nlo = lane & 31, khi = lane >> 5;
  const float bmv = bmean[w * 32 + nlo];
  const int m = t >> 3, j16 = t & 7;   // producer mapping: 8 lanes/edge

  // bijective chunked XCD swizzle (m204): nwg=2500, 8 XCDs, q=312, r=4.
  int bid;
  {
    int orig = blockIdx.x;
    int xcd = orig & 7, rank = orig >> 3;
    bid = (xcd < 4) ? xcd * 313 + rank : 4 * 313 + (xcd - 4) * 312 + rank;
  }

  const unsigned short* pw0 = W2F + (size_t)t * 8;

  // edge indices for tile 0 (tile k+1's prefetched during tile k)
  int snn = es[bid * 128 + m];
  int dnn = ed[bid * 128 + m];

  #pragma unroll 1
  for (int tt = 0; tt < 4; tt++) {
    const int e0 = bid * 128 + tt * 32;
    const int sn = snn, dn = dnn;

    if (tt < 3) {   // prefetch next tile's edge indices
      snn = es[e0 + 32 + m];
      dnn = ed[e0 + 32 + m];
    }

    // original edge ids for this thread's 16 output rows (broadcast loads,
    // issued early so they're covered by the gather phase)
    int eor[16];
    #pragma unroll
    for (int r = 0; r < 16; r++)
      eor[r] = eo[e0 + ((r & 3) + 8 * (r >> 2) + 4 * khi)];

    // ---- gather: 12 x 16B per thread (8 lanes share one edge) ----
    uint4 G[12];
    {
      const unsigned short* ps = Qsrc + (size_t)sn * (NS * OD) + j16 * 16;
      const unsigned short* pd = Qdst + (size_t)dn * (NS * OD) + j16 * 16;
      #pragma unroll
      for (int s = 0; s < NS; s++) {
        G[4 * s + 0] = *(const uint4*)(ps + s * OD);
        G[4 * s + 1] = *(const uint4*)(ps + s * OD + 8);
        G[4 * s + 2] = *(const uint4*)(pd + s * OD);
        G[4 * s + 3] = *(const uint4*)(pd + s * OD + 8);
      }
    }

    // ---- producer: h = relu(src + dst) -> LDS (swizzled frag layout) ----
    #pragma unroll
    for (int s = 0; s < NS; s++) {
      uint4 a0 = G[4 * s + 0], a1 = G[4 * s + 1];
      uint4 d0 = G[4 * s + 2], d1 = G[4 * s + 3];
      uint4 w0, w1;
      w0.x = relu2(a0.x, d0.x); w0.y = relu2(a0.y, d0.y);
      w0.z = relu2(a0.z, d0.z); w0.w = relu2(a0.w, d0.w);
      w1.x = relu2(a1.x, d1.x); w1.y = relu2(a1.y, d1.y);
      w1.z = relu2(a1.z, d1.z); w1.w = relu2(a1.w, d1.w);
      *(uint4*)(hsm + ((s * 8 + j16) * 64 + (m ^ j16)) * 8) = w0;
      *(uint4*)(hsm + ((s * 8 + j16) * 64 + ((32 + m) ^ j16)) * 8) = w1;
    }

    // ---- reload W2 fragments (L1/L2-hit; laundered ptr defeats LICM) ----
    const unsigned short* pw = pw0;
    asm volatile("" : "+v"(pw));
    bf16x8 fA[8], fB[8], fC[8];
    #pragma unroll
    for (int q = 0; q < 8; q++) fA[q] = *(const bf16x8*)(pw + (0 * 8 + q) * 2048);
    #pragma unroll
    for (int q = 0; q < 8; q++) fB[q] = *(const bf16x8*)(pw + (1 * 8 + q) * 2048);
    #pragma unroll
    for (int q = 0; q < 8; q++) fC[q] = *(const bf16x8*)(pw + (2 * 8 + q) * 2048);

    lds_barrier();

    // ---- consumer: C = sum_s h_s @ W2_s ----
    f32x16 C;
    #pragma unroll
    for (int i = 0; i < 16; i++) C[i] = 0.0f;
    __builtin_amdgcn_s_setprio(1);
    #pragma unroll
    for (int q = 0; q < 8; q++) {
      bf16x8 a = *(const bf16x8*)(hsm + ((0 * 8 + q) * 64 + (lane ^ q)) * 8);
      C = __builtin_amdgcn_mfma_f32_32x32x16_bf16(a, fA[q], C, 0, 0, 0);
    }
    #pragma unroll
    for (int q = 0; q < 8; q++) {
      bf16x8 a = *(const bf16x8*)(hsm + ((1 * 8 + q) * 64 + (lane ^ q)) * 8);
      C = __builtin_amdgcn_mfma_f32_32x32x16_bf16(a, fB[q], C, 0, 0, 0);
    }
    #pragma unroll
    for (int q = 0; q < 8; q++) {
      bf16x8 a = *(const bf16x8*)(hsm + ((2 * 8 + q) * 64 + (lane ^ q)) * 8);
      C = __builtin_amdgcn_mfma_f32_32x32x16_bf16(a, fC[q], C, 0, 0, 0);
    }
    __builtin_amdgcn_s_setprio(0);

    // ---- epilogue: scatter out = C/3 + bmean to original edge rows ----
    #pragma unroll
    for (int r = 0; r < 16; r++) {
      __builtin_nontemporal_store(C[r] * (1.0f / 3.0f) + bmv,
          &out[(size_t)eor[r] * OD + w * 32 + nlo]);
    }
    lds_barrier();
  }
}

extern "C" void kernel_launch(void* const* d_in, const int* in_sizes, int n_in,
                              void* d_out, int out_size, void* d_ws, size_t ws_size,
                              hipStream_t stream) {
  const float* nf       = (const float*)d_in[0];
  const float* temporal = (const float*)d_in[1];
  const float* W1       = (const float*)d_in[2];
  const float* b1       = (const float*)d_in[3];
  const float* W2       = (const float*)d_in[4];
  const float* b2       = (const float*)d_in[5];
  const int*   ei       = (const int*)d_in[6];
  float* out = (float*)d_out;

  char* ws = (char*)d_ws;
  unsigned short* Qsrc = (unsigned short*)ws;                         // 7,680,000 B
  unsigned short* Qdst = (unsigned short*)(ws + 7680000);             // 7,680,000 B
  unsigned short* W2F  = (unsigned short*)(ws + 15360000);            //    98,304 B
  float*          bmv  = (float*)(ws + 15458304);                     //       512 B
  int*            gh   = (int*)(ws + 15458816);                       //     1,600 B
  int*            cur  = (int*)(ws + 15460416);                       //     1,600 B
  int*            es   = (int*)(ws + 15462016);                       // 1,280,000 B
  int*            ed   = (int*)(ws + 16742016);                       // 1,280,000 B
  int*            eo   = (int*)(ws + 18022016);                       // 1,280,000 B

  prep_w2     <<<dim3(192),    dim3(256), 0, stream>>>(W2, b2, W2F, bmv);
  zero_aux    <<<dim3(2),      dim3(256), 0, stream>>>(gh);
  node_proj   <<<dim3(40, 6),  dim3(256), 0, stream>>>(nf, temporal, W1, b1, Qsrc, Qdst);
  edge_hist   <<<dim3(1250),   dim3(256), 0, stream>>>(ei, gh);
  bucket_scan <<<dim3(1),      dim3(512), 0, stream>>>(gh, cur);
  edge_scatter<<<dim3(1250),   dim3(256), 0, stream>>>(ei, cur, es, ed, eo);
  edge_mlp    <<<dim3(2500),   dim3(256), 0, stream>>>(Qsrc, Qdst, W2F, bmv, es, ed, eo, out);
}

// Round 5
// 299.891 us; speedup vs baseline: 1.4855x; 1.4855x over previous
//
#include <hip/hip_runtime.h>
#include <stdint.h>

#define NN 10000
#define NE 320000
#define DF 128
#define OD 128
#define NS 3

typedef __attribute__((ext_vector_type(8))) short bf16x8;
typedef __attribute__((ext_vector_type(16))) float f32x16;

static __device__ __forceinline__ uint32_t f2bf(float f) {
  uint32_t u = __float_as_uint(f);
  return (u + 0x7FFFu + ((u >> 16) & 1u)) >> 16;
}
static __device__ __forceinline__ float bflo(uint32_t u) { return __uint_as_float(u << 16); }
static __device__ __forceinline__ float bfhi(uint32_t u) { return __uint_as_float(u & 0xFFFF0000u); }

static __device__ __forceinline__ uint32_t relu2(uint32_t a, uint32_t d) {
  float f0 = fmaxf(bflo(a) + bflo(d), 0.0f);
  float f1 = fmaxf(bfhi(a) + bfhi(d), 0.0f);
  return f2bf(f0) | (f2bf(f1) << 16);
}

// ---------------------------------------------------------------------------
// Kernel 0: W2 [3][128][128] fp32 -> W2F fragment-major bf16 (unchanged):
//   W2F[(((s*8+q)*4 + nb)*64 + lane)*8 + jj] holds B-frag element for
//   n = nb*32 + (lane&31), k = q*16 + (lane>>5)*8 + jj.
// Also bmean = mean_s b2.
// ---------------------------------------------------------------------------
__global__ __launch_bounds__(256) void prep_w2(
    const float* __restrict__ W2, const float* __restrict__ b2,
    unsigned short* __restrict__ w2f, float* __restrict__ bmean)
{
  int o = blockIdx.x * 256 + threadIdx.x;
  if (o < NS * 8 * 256 * 8) {
    int j = o & 7;
    int t = (o >> 3) & 255;
    int q = (o >> 11) & 7;
    int s = o >> 14;
    int w = t >> 6, lane = t & 63;
    int n = w * 32 + (lane & 31);
    int k = q * 16 + (lane >> 5) * 8 + j;
    w2f[o] = (unsigned short)f2bf(W2[((size_t)s * OD + k) * OD + n]);
  }
  if (o < OD) bmean[o] = (b2[o] + b2[OD + o] + b2[2 * OD + o]) * (1.0f / 3.0f);
}

// ---------------------------------------------------------------------------
// Kernel 1: per-node projections (unchanged — ~7 us, not the bottleneck)
// ---------------------------------------------------------------------------
__global__ __launch_bounds__(256) void node_proj(
    const float* __restrict__ nf, const float* __restrict__ temporal,
    const float* __restrict__ W1, const float* __restrict__ b1,
    unsigned short* __restrict__ Qsrc, unsigned short* __restrict__ Qdst)
{
  __shared__ unsigned short Asm[8 * 64 * 8];
  __shared__ unsigned short Bsm[4 * 8 * 64 * 8];
  __shared__ float tsh[32];

  const int t = threadIdx.x;
  const int c = blockIdx.y;
  const int s = c >> 1, proj = c & 1;

  {
    int o = t & 127, qh = t >> 7;
    const float* wbase = W1 + (size_t)(s * 257 + proj * 128) * OD + o;
    int nt = o >> 5, lnlo = o & 31;
    #pragma unroll
    for (int r = 0; r < 8; r++) {
      int kh = qh * 8 + r;
      float v[8];
      #pragma unroll
      for (int j = 0; j < 8; j++) v[j] = wbase[(size_t)(kh * 8 + j) * OD];
      uint32_t pk[4];
      #pragma unroll
      for (int i = 0; i < 4; i++) pk[i] = f2bf(v[2 * i]) | (f2bf(v[2 * i + 1]) << 16);
      int q = kh >> 1, half = kh & 1;
      uint32_t* d = (uint32_t*)(Bsm + ((nt * 8 + q) * 64 + half * 32 + lnlo) * 8);
      d[0] = pk[0]; d[1] = pk[1]; d[2] = pk[2]; d[3] = pk[3];
    }
  }

  const int lane = t & 63, w = t >> 6;
  const int o = w * 32 + (lane & 31);
  const float w1gv = W1[(size_t)(s * 257 + 256) * OD + o];
  const float b1v = b1[s * OD + o];
  unsigned short* Qt = (proj == 0) ? Qsrc : Qdst;
  const int m = t >> 3, j16 = t & 7;

  for (int it = 0; it < 8; it++) {
    const int m0 = (blockIdx.x * 8 + it) * 32;
    if (m0 >= NN) break;

    if (t < 32) tsh[t] = (m0 + t < NN) ? temporal[m0 + t] : 0.0f;

    {
      int node = m0 + m;
      float v[16];
      if (node < NN) {
        const float4* p = (const float4*)(nf + (size_t)node * DF + j16 * 16);
        #pragma unroll
        for (int i = 0; i < 4; i++) {
          float4 x = p[i];
          v[4 * i] = x.x; v[4 * i + 1] = x.y; v[4 * i + 2] = x.z; v[4 * i + 3] = x.w;
        }
      } else {
        #pragma unroll
        for (int i = 0; i < 16; i++) v[i] = 0.0f;
      }
      uint32_t pk[8];
      #pragma unroll
      for (int i = 0; i < 8; i++) pk[i] = f2bf(v[2 * i]) | (f2bf(v[2 * i + 1]) << 16);
      uint32_t* d0 = (uint32_t*)(Asm + (j16 * 64 + (m ^ j16)) * 8);
      uint32_t* d1 = (uint32_t*)(Asm + (j16 * 64 + ((32 + m) ^ j16)) * 8);
      d0[0] = pk[0]; d0[1] = pk[1]; d0[2] = pk[2]; d0[3] = pk[3];
      d1[0] = pk[4]; d1[1] = pk[5]; d1[2] = pk[6]; d1[3] = pk[7];
    }
    __syncthreads();

    f32x16 C;
    #pragma unroll
    for (int i = 0; i < 16; i++) C[i] = 0.0f;
    #pragma unroll
    for (int q = 0; q < 8; q++) {
      bf16x8 a = *(const bf16x8*)(Asm + (q * 64 + (lane ^ q)) * 8);
      bf16x8 b = *(const bf16x8*)(Bsm + ((w * 8 + q) * 64 + lane) * 8);
      C = __builtin_amdgcn_mfma_f32_32x32x16_bf16(a, b, C, 0, 0, 0);
    }

    #pragma unroll
    for (int r = 0; r < 16; r++) {
      int row = (r & 3) + 8 * (r >> 2) + 4 * (lane >> 5);
      int node = m0 + row;
      if (node < NN) {
        float val = C[r];
        if (proj == 0) val += b1v + tsh[row] * w1gv;
        else           val -= tsh[row] * w1gv;
        Qt[(size_t)node * (NS * OD) + s * OD + o] = (unsigned short)f2bf(val);
      }
    }
    __syncthreads();
  }
}

// ---------------------------------------------------------------------------
// Kernel 2: BARRIER-FREE wave-autonomous edge MLP. Each wave owns one
// 32-edge tile: cooperative per-scale gather (16 lanes x 16B = one 256B
// scale-row, 4 edges/instr), relu-pack into a WAVE-PRIVATE 8KB LDS half
// (slot-XOR layout, conflict-free), ds_read own A-frags — same-wave
// producer/consumer needs only lgkmcnt, no s_barrier anywhere.
// 3-scale software pipeline: gathers(s+1) issue -> ds_read A(s) ->
// B-loads + 32 MFMA(s) [covers gather latency] -> relu+write(s+1).
// ---------------------------------------------------------------------------
__global__ __launch_bounds__(256, 2) void edge_mlp(
    const unsigned short* __restrict__ Qsrc, const unsigned short* __restrict__ Qdst,
    const unsigned short* __restrict__ W2F, const float* __restrict__ bmean,
    const int* __restrict__ ei, float* __restrict__ out)
{
  __shared__ unsigned short hsm[4][2][8 * 64 * 8];   // [wave][dbuf][8KB] = 64KB

  const int t = threadIdx.x;
  const int lane = t & 63, w = t >> 6;
  const int e0 = (blockIdx.x * 4 + w) * 32;          // this wave's 32 edges
  const int r31 = lane & 31;
  const int esub = lane >> 4;                        // 0..3: edge within batch
  const int p = lane & 15;                           // 16B piece of 256B row
  const int j = p >> 1, kh = p & 1;                  // LDS row / k-half

  // edge node ids: lane L holds indices for edge e0 + (L&31)
  const int sn = ei[e0 + r31];
  const int dn = ei[NE + e0 + r31];

  float bm[4];
  #pragma unroll
  for (int nb = 0; nb < 4; nb++) bm[nb] = bmean[nb * 32 + r31];

  unsigned short* buf0 = hsm[w][0];
  unsigned short* buf1 = hsm[w][1];

  uint4 ga[8], gd[8];   // gather staging: batch b = edges 4b..4b+3

#define GLOAD(S) do {                                                         \
    _Pragma("unroll") for (int b = 0; b < 8; b++) {                           \
      int se = __shfl(sn, 4 * b + esub);                                      \
      int de = __shfl(dn, 4 * b + esub);                                      \
      ga[b] = *(const uint4*)(Qsrc + (size_t)se * (NS * OD) + (S) * OD + p * 8); \
      gd[b] = *(const uint4*)(Qdst + (size_t)de * (NS * OD) + (S) * OD + p * 8); \
    } } while (0)

#define GWRITE(BUF) do {                                                      \
    _Pragma("unroll") for (int b = 0; b < 8; b++) {                           \
      uint4 h;                                                                \
      h.x = relu2(ga[b].x, gd[b].x); h.y = relu2(ga[b].y, gd[b].y);           \
      h.z = relu2(ga[b].z, gd[b].z); h.w = relu2(ga[b].w, gd[b].w);           \
      int e = 4 * b + esub;                                                   \
      *(uint4*)((BUF) + ((size_t)j * 64 + ((kh * 32 + e) ^ j)) * 8) = h;      \
    } } while (0)

  f32x16 C[4];
  #pragma unroll
  for (int nb = 0; nb < 4; nb++)
    #pragma unroll
    for (int i = 0; i < 16; i++) C[nb][i] = 0.0f;

  // prologue: produce scale 0 (only place gather latency is exposed)
  GLOAD(0);
  GWRITE(buf0);

  #pragma unroll
  for (int s = 0; s < NS; s++) {
    unsigned short* cb   = (s & 1) ? buf1 : buf0;
    unsigned short* nbuf = (s & 1) ? buf0 : buf1;

    if (s == 0) GLOAD(1);         // issue next scale's gathers early
    else if (s == 1) GLOAD(2);

    bf16x8 af[8];
    #pragma unroll
    for (int q = 0; q < 8; q++)
      af[q] = *(const bf16x8*)(cb + (q * 64 + (lane ^ q)) * 8);

    #pragma unroll
    for (int nb = 0; nb < 4; nb++) {
      #pragma unroll
      for (int q = 0; q < 8; q++) {
        bf16x8 bf = *(const bf16x8*)(W2F +
            (size_t)((((s * 8 + q) * 4 + nb) * 64 + lane)) * 8);
        C[nb] = __builtin_amdgcn_mfma_f32_32x32x16_bf16(af[q], bf, C[nb], 0, 0, 0);
      }
    }

    if (s < 2) GWRITE(nbuf);      // vmcnt wait lands here, after MFMA cover
  }
#undef GLOAD
#undef GWRITE

  // epilogue: out = (sum_s) / 3 + bmean
  #pragma unroll
  for (int nb = 0; nb < 4; nb++) {
    #pragma unroll
    for (int r = 0; r < 16; r++) {
      int row = (r & 3) + 8 * (r >> 2) + 4 * (lane >> 5);
      out[(size_t)(e0 + row) * OD + nb * 32 + r31] = C[nb][r] * (1.0f / 3.0f) + bm[nb];
    }
  }
}

extern "C" void kernel_launch(void* const* d_in, const int* in_sizes, int n_in,
                              void* d_out, int out_size, void* d_ws, size_t ws_size,
                              hipStream_t stream) {
  const float* nf       = (const float*)d_in[0];
  const float* temporal = (const float*)d_in[1];
  const float* W1       = (const float*)d_in[2];
  const float* b1       = (const float*)d_in[3];
  const float* W2       = (const float*)d_in[4];
  const float* b2       = (const float*)d_in[5];
  const int*   ei       = (const int*)d_in[6];
  float* out = (float*)d_out;

  char* ws = (char*)d_ws;
  unsigned short* Qsrc = (unsigned short*)ws;                       // 7,680,000 B
  unsigned short* Qdst = (unsigned short*)(ws + 7680000);           // 7,680,000 B
  unsigned short* W2F  = (unsigned short*)(ws + 15360000);          // 98,304 B
  float*          bmv  = (float*)(ws + 15360000 + 98304);           // 512 B

  prep_w2  <<<dim3(192),    dim3(256), 0, stream>>>(W2, b2, W2F, bmv);
  node_proj<<<dim3(40, 6),  dim3(256), 0, stream>>>(nf, temporal, W1, b1, Qsrc, Qdst);
  edge_mlp <<<dim3(2500),   dim3(256), 0, stream>>>(Qsrc, Qdst, W2F, bmv, ei, out);
}

// Round 6
// 261.935 us; speedup vs baseline: 1.7007x; 1.1449x over previous
//
#include <hip/hip_runtime.h>
#include <stdint.h>

#define NN 10000
#define NE 320000
#define DF 128
#define OD 128
#define NS 3

typedef __attribute__((ext_vector_type(8))) short bf16x8;
typedef __attribute__((ext_vector_type(16))) float f32x16;

static __device__ __forceinline__ uint32_t f2bf(float f) {
  uint32_t u = __float_as_uint(f);
  return (u + 0x7FFFu + ((u >> 16) & 1u)) >> 16;
}
static __device__ __forceinline__ float bflo(uint32_t u) { return __uint_as_float(u << 16); }
static __device__ __forceinline__ float bfhi(uint32_t u) { return __uint_as_float(u & 0xFFFF0000u); }

// relu2 via hardware packed convert: v_cvt_pk_bf16_f32 (RNE, bit-identical
// to the manual round-nearest-even pack it replaces, ~1/3 the VALU ops).
static __device__ __forceinline__ uint32_t relu2(uint32_t a, uint32_t d) {
  float f0 = fmaxf(bflo(a) + bflo(d), 0.0f);
  float f1 = fmaxf(bfhi(a) + bfhi(d), 0.0f);
  uint32_t r;
  asm("v_cvt_pk_bf16_f32 %0, %1, %2" : "=v"(r) : "v"(f0), "v"(f1));
  return r;
}

// lgkm-only barrier: orders LDS producer/consumer without draining vmcnt —
// gather prefetch + out-stores stay in flight across the barrier.
static __device__ __forceinline__ void lds_barrier() {
  asm volatile("s_waitcnt lgkmcnt(0)" ::: "memory");
  __builtin_amdgcn_s_barrier();
}

// ---------------------------------------------------------------------------
// Kernel 1 (FUSED): per-node projections + W2 transpose prep + bmean.
// 240 blocks x 256 threads: the prep work (49152 W2T elems + 128 bmean) is
// distributed one element per thread across the grid's first 49152 threads —
// removes the separate prep_w2 launch from the timed graph.
// ---------------------------------------------------------------------------
__global__ __launch_bounds__(256) void node_proj(
    const float* __restrict__ nf, const float* __restrict__ temporal,
    const float* __restrict__ W1, const float* __restrict__ b1,
    const float* __restrict__ W2, const float* __restrict__ b2,
    unsigned short* __restrict__ w2t, float* __restrict__ bmean,
    unsigned short* __restrict__ Qsrc, unsigned short* __restrict__ Qdst)
{
  __shared__ unsigned short Asm[8 * 64 * 8];       // 8 KB, swizzled frag layout
  __shared__ unsigned short Bsm[4 * 8 * 64 * 8];   // 32 KB
  __shared__ float tsh[32];

  const int t = threadIdx.x;
  const int c = blockIdx.y;
  const int s = c >> 1, proj = c & 1;

  // ---- fused prep_w2: one element per thread over the 240x256 grid ----
  {
    int o = (blockIdx.y * 40 + blockIdx.x) * 256 + t;   // 0..61439
    if (o < NS * OD * OD) {
      int ss = o / (OD * OD);
      int r = o % (OD * OD);
      int k = r / OD;
      int n = r % OD;
      w2t[(ss * OD + n) * OD + k] = (unsigned short)f2bf(W2[o]);
    }
    if (o < OD) bmean[o] = (b2[o] + b2[OD + o] + b2[2 * OD + o]) * (1.0f / 3.0f);
  }

  {
    int o = t & 127, qh = t >> 7;
    const float* wbase = W1 + (size_t)(s * 257 + proj * 128) * OD + o;
    int nt = o >> 5, lnlo = o & 31;
    #pragma unroll
    for (int r = 0; r < 8; r++) {
      int kh = qh * 8 + r;
      float v[8];
      #pragma unroll
      for (int j = 0; j < 8; j++) v[j] = wbase[(size_t)(kh * 8 + j) * OD];
      uint32_t pk[4];
      #pragma unroll
      for (int i = 0; i < 4; i++) pk[i] = f2bf(v[2 * i]) | (f2bf(v[2 * i + 1]) << 16);
      int q = kh >> 1, half = kh & 1;
      uint32_t* d = (uint32_t*)(Bsm + ((nt * 8 + q) * 64 + half * 32 + lnlo) * 8);
      d[0] = pk[0]; d[1] = pk[1]; d[2] = pk[2]; d[3] = pk[3];
    }
  }

  const int lane = t & 63, w = t >> 6;
  const int o = w * 32 + (lane & 31);
  const float w1gv = W1[(size_t)(s * 257 + 256) * OD + o];
  const float b1v = b1[s * OD + o];
  unsigned short* Qt = (proj == 0) ? Qsrc : Qdst;
  const int m = t >> 3, j16 = t & 7;

  for (int it = 0; it < 8; it++) {
    const int m0 = (blockIdx.x * 8 + it) * 32;
    if (m0 >= NN) break;                            // block-uniform

    if (t < 32) tsh[t] = (m0 + t < NN) ? temporal[m0 + t] : 0.0f;

    {
      int node = m0 + m;
      float v[16];
      if (node < NN) {
        const float4* p = (const float4*)(nf + (size_t)node * DF + j16 * 16);
        #pragma unroll
        for (int i = 0; i < 4; i++) {
          float4 x = p[i];
          v[4 * i] = x.x; v[4 * i + 1] = x.y; v[4 * i + 2] = x.z; v[4 * i + 3] = x.w;
        }
      } else {
        #pragma unroll
        for (int i = 0; i < 16; i++) v[i] = 0.0f;
      }
      uint32_t pk[8];
      #pragma unroll
      for (int i = 0; i < 8; i++) pk[i] = f2bf(v[2 * i]) | (f2bf(v[2 * i + 1]) << 16);
      uint32_t* d0 = (uint32_t*)(Asm + (j16 * 64 + (m ^ j16)) * 8);
      uint32_t* d1 = (uint32_t*)(Asm + (j16 * 64 + ((32 + m) ^ j16)) * 8);
      d0[0] = pk[0]; d0[1] = pk[1]; d0[2] = pk[2]; d0[3] = pk[3];
      d1[0] = pk[4]; d1[1] = pk[5]; d1[2] = pk[6]; d1[3] = pk[7];
    }
    __syncthreads();

    f32x16 C;
    #pragma unroll
    for (int i = 0; i < 16; i++) C[i] = 0.0f;
    #pragma unroll
    for (int q = 0; q < 8; q++) {
      bf16x8 a = *(const bf16x8*)(Asm + (q * 64 + (lane ^ q)) * 8);
      bf16x8 b = *(const bf16x8*)(Bsm + ((w * 8 + q) * 64 + lane) * 8);
      C = __builtin_amdgcn_mfma_f32_32x32x16_bf16(a, b, C, 0, 0, 0);
    }

    #pragma unroll
    for (int r = 0; r < 16; r++) {
      int row = (r & 3) + 8 * (r >> 2) + 4 * (lane >> 5);
      int node = m0 + row;
      if (node < NN) {
        float val = C[r];
        if (proj == 0) val += b1v + tsh[row] * w1gv;
        else           val -= tsh[row] * w1gv;
        Qt[(size_t)node * (NS * OD) + s * OD + o] = (unsigned short)f2bf(val);
      }
    }
    __syncthreads();
  }
}

// ---------------------------------------------------------------------------
// Kernel 2: proven R2 structure (2500 blocks x 4 tiles, persistent bfrag,
// G2 register prefetch, lgkm-only barriers, setprio, NT stores) with:
//  - cvt_pk relu2 (producer VALU cut ~2x)
//  - parity-unrolled tile steps (no 12-reg G=G2 copy per tile)
// ---------------------------------------------------------------------------
__global__ __launch_bounds__(256) void edge_mlp(
    const unsigned short* __restrict__ Qsrc, const unsigned short* __restrict__ Qdst,
    const unsigned short* __restrict__ W2T, const float* __restrict__ bmean,
    const int* __restrict__ ei, float* __restrict__ out)
{
  __shared__ unsigned short hsm[NS * 8 * 64 * 8];   // 24 KB, swizzled frag layout

  const int t = threadIdx.x;
  const int lane = t & 63, w = t >> 6;
  const int nlo = lane & 31, khi = lane >> 5;

  // persistent B fragments: W2T[s][n][k], k contiguous
  bf16x8 bfrag[NS][8];
  {
    int n = w * 32 + nlo;
    #pragma unroll
    for (int s = 0; s < NS; s++) {
      const unsigned short* base = W2T + ((s * OD + n) * OD + khi * 8);
      #pragma unroll
      for (int q = 0; q < 8; q++)
        bfrag[s][q] = *(const bf16x8*)(base + q * 16);
    }
  }
  const float bmv = bmean[w * 32 + nlo];

  const int m = t >> 3, j16 = t & 7;   // producer mapping: 8 lanes/edge

  // all 4 tiles' edge indices up front
  int sn[4], dn[4];
  #pragma unroll
  for (int tt = 0; tt < 4; tt++) {
    int e = blockIdx.x * 128 + tt * 32 + m;
    sn[tt] = ei[e];
    dn[tt] = ei[NE + e];
  }

  uint4 GA[12], GB[12];

#define GATHER(DST, TT) do {                                                  \
    const unsigned short* ps = Qsrc + (size_t)sn[TT] * (NS * OD) + j16 * 16;  \
    const unsigned short* pd = Qdst + (size_t)dn[TT] * (NS * OD) + j16 * 16;  \
    _Pragma("unroll") for (int s = 0; s < NS; s++) {                          \
      DST[4 * s + 0] = *(const uint4*)(ps + s * OD);                          \
      DST[4 * s + 1] = *(const uint4*)(ps + s * OD + 8);                      \
      DST[4 * s + 2] = *(const uint4*)(pd + s * OD);                          \
      DST[4 * s + 3] = *(const uint4*)(pd + s * OD + 8);                      \
    } } while (0)

  // STEP: consume GC (producer), prefetch tile TT+1 into GN, MFMA, store.
#define STEP(TT, GC, GN) do {                                                 \
    const int e0 = blockIdx.x * 128 + (TT) * 32;                              \
    _Pragma("unroll") for (int s = 0; s < NS; s++) {                          \
      uint4 a0 = GC[4 * s + 0], a1 = GC[4 * s + 1];                           \
      uint4 d0 = GC[4 * s + 2], d1 = GC[4 * s + 3];                           \
      uint4 w0, w1;                                                           \
      w0.x = relu2(a0.x, d0.x); w0.y = relu2(a0.y, d0.y);                     \
      w0.z = relu2(a0.z, d0.z); w0.w = relu2(a0.w, d0.w);                     \
      w1.x = relu2(a1.x, d1.x); w1.y = relu2(a1.y, d1.y);                     \
      w1.z = relu2(a1.z, d1.z); w1.w = relu2(a1.w, d1.w);                     \
      *(uint4*)(hsm + ((s * 8 + j16) * 64 + (m ^ j16)) * 8) = w0;             \
      *(uint4*)(hsm + ((s * 8 + j16) * 64 + ((32 + m) ^ j16)) * 8) = w1;      \
    }                                                                         \
    if ((TT) < 3) GATHER(GN, (TT) + 1);                                       \
    lds_barrier();                                                            \
    f32x16 C;                                                                 \
    _Pragma("unroll") for (int i = 0; i < 16; i++) C[i] = 0.0f;               \
    __builtin_amdgcn_s_setprio(1);                                            \
    _Pragma("unroll") for (int s = 0; s < NS; s++) {                          \
      _Pragma("unroll") for (int q = 0; q < 8; q++) {                         \
        bf16x8 a = *(const bf16x8*)(hsm + ((s * 8 + q) * 64 + (lane ^ q)) * 8); \
        C = __builtin_amdgcn_mfma_f32_32x32x16_bf16(a, bfrag[s][q], C, 0, 0, 0); \
      }                                                                       \
    }                                                                         \
    __builtin_amdgcn_s_setprio(0);                                            \
    _Pragma("unroll") for (int r = 0; r < 16; r++) {                          \
      int row = (r & 3) + 8 * (r >> 2) + 4 * khi;                             \
      __builtin_nontemporal_store(C[r] * (1.0f / 3.0f) + bmv,                 \
          &out[(size_t)(e0 + row) * OD + w * 32 + nlo]);                      \
    }                                                                         \
    lds_barrier();                                                            \
  } while (0)

  GATHER(GA, 0);
  STEP(0, GA, GB);
  STEP(1, GB, GA);
  STEP(2, GA, GB);
  STEP(3, GB, GA);

#undef STEP
#undef GATHER
}

extern "C" void kernel_launch(void* const* d_in, const int* in_sizes, int n_in,
                              void* d_out, int out_size, void* d_ws, size_t ws_size,
                              hipStream_t stream) {
  const float* nf       = (const float*)d_in[0];
  const float* temporal = (const float*)d_in[1];
  const float* W1       = (const float*)d_in[2];
  const float* b1       = (const float*)d_in[3];
  const float* W2       = (const float*)d_in[4];
  const float* b2       = (const float*)d_in[5];
  const int*   ei       = (const int*)d_in[6];
  float* out = (float*)d_out;

  char* ws = (char*)d_ws;
  unsigned short* Qsrc = (unsigned short*)ws;                       // 7,680,000 B
  unsigned short* Qdst = (unsigned short*)(ws + 7680000);           // 7,680,000 B
  unsigned short* W2T  = (unsigned short*)(ws + 15360000);          // 98,304 B
  float*          bmv  = (float*)(ws + 15360000 + 98304);           // 512 B

  node_proj<<<dim3(40, 6), dim3(256), 0, stream>>>(
      nf, temporal, W1, b1, W2, b2, W2T, bmv, Qsrc, Qdst);
  edge_mlp <<<dim3(2500),  dim3(256), 0, stream>>>(Qsrc, Qdst, W2T, bmv, ei, out);
}